// Round 9
// baseline (325.354 us; speedup 1.0000x reference)
//
#include <hip/hip_runtime.h>
#include <stdint.h>

typedef unsigned short ushort;
typedef __attribute__((ext_vector_type(8))) short bf16x8;
typedef __attribute__((ext_vector_type(4))) float f32x4;
typedef __attribute__((ext_vector_type(16))) float f32x16;

// ---- bf16 helpers (bit-level) ----
__device__ __forceinline__ float b2f(ushort u) {
    return __uint_as_float(((unsigned)u) << 16);
}
__device__ __forceinline__ ushort f2b(float f) {
    unsigned u = __float_as_uint(f);
    u += 0x7fff + ((u >> 16) & 1);   // round-to-nearest-even
    return (ushort)(u >> 16);
}

// exp2 (native v_exp_f32), compile-safe
#if __has_builtin(__builtin_amdgcn_exp2f)
#define EXP2(x) __builtin_amdgcn_exp2f(x)
#else
#define EXP2(x) __expf((x) * 0.69314718056f)
#endif

// v_cvt_pk_bf16_f32: pack 2 f32 -> 2 bf16 in one u32 (RNE)
__device__ __forceinline__ unsigned cvtpk(float a, float b) {
    unsigned r;
    asm("v_cvt_pk_bf16_f32 %0, %1, %2" : "=v"(r) : "v"(a), "v"(b));
    return r;
}

// v_permlane32_swap_b32: exchange halves across lane<32 / lane>=32.
__device__ __forceinline__ void plswap(unsigned &a, unsigned &b) {
#if __has_builtin(__builtin_amdgcn_permlane32_swap)
    auto r = __builtin_amdgcn_permlane32_swap(a, b, 0, 0);
    a = (unsigned)r[0]; b = (unsigned)r[1];
#else
    asm volatile("v_permlane32_swap_b32 %0, %1" : "+v"(a), "+v"(b));
#endif
}

// Problem constants: B=4, N=2048, C=1024, H=16, D=64, M = B*N = 8192
#define SEQN 2048
#define EMB  1024
#define NH   16
#define HD   64
#define BHSTRIDE (SEQN * HD)   // 131072 elems per (b,h) plane

// async global->LDS, 16B per lane; LDS dest = wave-uniform base + lane*16
__device__ __forceinline__ void gload16(const ushort* g, ushort* l) {
    __builtin_amdgcn_global_load_lds(
        (const __attribute__((address_space(1))) unsigned int*)g,
        (__attribute__((address_space(3))) unsigned int*)l, 16, 0, 0);
}

// =====================================================================
// Kernel A: fp32 -> bf16 pre-conversion (x), grid exact: 4096 x 256
// =====================================================================
__global__ __launch_bounds__(256) void conv_x(
        const float* __restrict__ s, ushort* __restrict__ d) {
    const size_t i = (size_t)blockIdx.x * 256 + threadIdx.x;
    float4 a = ((const float4*)s)[2 * i];
    float4 b = ((const float4*)s)[2 * i + 1];
    ushort pk[8] = {f2b(a.x), f2b(a.y), f2b(a.z), f2b(a.w),
                    f2b(b.x), f2b(b.y), f2b(b.z), f2b(b.w)};
    ((uint4*)d)[i] = *(uint4*)pk;
}

// Kernel B: convert the 4 weight matrices into one contiguous bf16 buffer
__global__ __launch_bounds__(256) void conv_w4(
        const float* __restrict__ W0, const float* __restrict__ W1,
        const float* __restrict__ W2, const float* __restrict__ W3,
        ushort* __restrict__ d) {
    const float* s = (blockIdx.y == 0) ? W0 : (blockIdx.y == 1) ? W1
                   : (blockIdx.y == 2) ? W2 : W3;
    ushort* dst = d + ((size_t)blockIdx.y << 20);
    const size_t i = (size_t)blockIdx.x * 256 + threadIdx.x;
    float4 a = ((const float4*)s)[2 * i];
    float4 b = ((const float4*)s)[2 * i + 1];
    ushort pk[8] = {f2b(a.x), f2b(a.y), f2b(a.z), f2b(a.w),
                    f2b(b.x), f2b(b.y), f2b(b.z), f2b(b.w)};
    ((uint4*)dst)[i] = *(uint4*)pk;
}

// =====================================================================
// Kernel C: PERMUTED log2-domain bias table, f32.
// Lp[qt][kv4][lo] (float4 over kv&3), qt = q>>5, lo = q&31.
// =====================================================================
__global__ __launch_bounds__(256) void conv_Lp(
        const float* __restrict__ dist, const float* __restrict__ dw,
        const float* __restrict__ db, float* __restrict__ Lp) {
    const float c1 = dw[0] * 1.44269504f, c2 = db[0] * 1.44269504f;
    const size_t gid = (size_t)blockIdx.x * 256 + threadIdx.x;
    const int lo  = (int)(gid & 31);
    const int kv4 = (int)((gid >> 5) & 511);
    const int qt  = (int)(gid >> 14);
    const int q   = qt * 32 + lo;
    float4 d = *(const float4*)(dist + (size_t)q * SEQN + kv4 * 4);
    float4 o = {fmaf(d.x, c1, c2), fmaf(d.y, c1, c2),
                fmaf(d.z, c1, c2), fmaf(d.w, c1, c2)};
    ((float4*)Lp)[gid] = o;
}

// =====================================================================
// GEMM pieces: 128x128 tile, BK=32, TILE-double-buffered LDS with the
// T3 "minimum 2-phase" pipeline: stage tile t+1 into the alternate
// buffer BEFORE computing tile t; ONE trailing __syncthreads per tile
// (its built-in vmcnt(0)+lgkmcnt(0) drain is the completion guarantee).
// Race analysis: stage into buf[cur^1] follows the barrier that ended
// iteration t-1, whose compute was the last reader of buf[cur^1].
// Same barrier count as the old serial structure; the global-load
// latency now overlaps the compute phase instead of being exposed.
// =====================================================================
#define LDSZ (128 * 32)   // shorts per tile buffer (8 KB)

// =====================================================================
// Kernel 1: fused QKV projection.  grid = (M/128, 3*8)
// q/k blocks use SWAPPED MFMA operands (regs run along output channel
// -> packed uint2 epilogue); v keeps original orientation.
// =====================================================================
__global__ __launch_bounds__(256) void gemm_qkv(
        const ushort* __restrict__ xb, const ushort* __restrict__ Wb,
        const float* __restrict__ bq, const float* __restrict__ bk,
        const float* __restrict__ bv,
        ushort* __restrict__ qb, ushort* __restrict__ kb,
        ushort* __restrict__ vT) {
    __shared__ ushort As[2][LDSZ];
    __shared__ ushort Bs[2][LDSZ];
    const int m0   = blockIdx.x * 128;
    const int nt   = blockIdx.y;           // 0..23
    const int wsel = nt >> 3;
    const int n0   = (nt & 7) * 128;
    const ushort* W    = Wb + ((size_t)wsel << 20);
    const float* bias  = (wsel == 0) ? bq : (wsel == 1) ? bk : bv;

    const int t = threadIdx.x, lane = t & 63, wave = t >> 6;
    const int ln = lane & 15, quad = lane >> 4;
    const int wm = wave & 1, wn = wave >> 1;

    const int e0 = wave * 128 + lane;
    const int e1 = e0 + 64;
    const ushort* gA0 = xb + (size_t)(m0 + (e0 >> 2)) * 1024 + (e0 & 3) * 8;
    const ushort* gA1 = xb + (size_t)(m0 + (e1 >> 2)) * 1024 + (e1 & 3) * 8;
    const ushort* gB0 = W  + (size_t)(n0 + (e0 >> 2)) * 1024 + (e0 & 3) * 8;
    const ushort* gB1 = W  + (size_t)(n0 + (e1 >> 2)) * 1024 + (e1 & 3) * 8;
    const int lofs = wave * 1024;          // wave-uniform LDS chunk base

    f32x4 acc[4][4];
#pragma unroll
    for (int i = 0; i < 4; i++)
#pragma unroll
        for (int j = 0; j < 4; j++) acc[i][j] = (f32x4){0.f, 0.f, 0.f, 0.f};

    // ---- prologue: stage tile 0 into buf0 ----
    gload16(gA0, &As[0][lofs]); gload16(gA1, &As[0][lofs + 512]);
    gload16(gB0, &Bs[0][lofs]); gload16(gB1, &Bs[0][lofs + 512]);
    __syncthreads();

#pragma unroll 2
    for (int kt = 0; kt < 32; kt++) {
        const int cur = kt & 1;            // static under unroll 2
        // ---- issue stage of tile kt+1 into alt buffer (overlaps MFMA) ----
        if (kt < 31) {
            const int k0n = kt * 32 + 32;
            gload16(gA0 + k0n, &As[cur ^ 1][lofs]);
            gload16(gA1 + k0n, &As[cur ^ 1][lofs + 512]);
            gload16(gB0 + k0n, &Bs[cur ^ 1][lofs]);
            gload16(gB1 + k0n, &Bs[cur ^ 1][lofs + 512]);
        }
        // ---- compute tile kt from buf[cur] ----
        bf16x8 af[4], bfr[4];
#pragma unroll
        for (int i = 0; i < 4; i++)
            af[i]  = *(bf16x8*)&As[cur][(wm * 64 + i * 16 + ln) * 32 + quad * 8];
#pragma unroll
        for (int j = 0; j < 4; j++)
            bfr[j] = *(bf16x8*)&Bs[cur][(wn * 64 + j * 16 + ln) * 32 + quad * 8];
        if (wsel < 2) {
            // swapped: D[o][m] -> acc[j][i] regs run along o
#pragma unroll
            for (int j = 0; j < 4; j++)
#pragma unroll
                for (int i = 0; i < 4; i++)
                    acc[j][i] = __builtin_amdgcn_mfma_f32_16x16x32_bf16(
                                    bfr[j], af[i], acc[j][i], 0, 0, 0);
        } else {
#pragma unroll
            for (int i = 0; i < 4; i++)
#pragma unroll
                for (int j = 0; j < 4; j++)
                    acc[i][j] = __builtin_amdgcn_mfma_f32_16x16x32_bf16(
                                    af[i], bfr[j], acc[i][j], 0, 0, 0);
        }
        __syncthreads();   // drains vmcnt (stage kt+1 done) + joins readers
    }

    if (wsel < 2) {
        // swapped layout: o = n0+wn*64+j*16+quad*4+r, m = m0+wm*64+i*16+ln
        ushort* dst = (wsel == 0) ? qb : kb;
        const float scale = (wsel == 0) ? 0.125f : 1.0f;   // q pre-scaled
#pragma unroll
        for (int j = 0; j < 4; j++) {
            const int o0 = n0 + wn * 64 + j * 16 + quad * 4;  // 4 consecutive o
            const int h  = o0 >> 6, d0 = o0 & 63;
            const float b0 = bias[o0], b1 = bias[o0 + 1];
            const float b2 = bias[o0 + 2], b3 = bias[o0 + 3];
#pragma unroll
            for (int i = 0; i < 4; i++) {
                const int m  = m0 + wm * 64 + i * 16 + ln;
                const int bb = m >> 11;
                const int ns = m & 2047;
                uint2 pk2;
                pk2.x = cvtpk((acc[j][i][0] + b0) * scale,
                              (acc[j][i][1] + b1) * scale);
                pk2.y = cvtpk((acc[j][i][2] + b2) * scale,
                              (acc[j][i][3] + b3) * scale);
                *(uint2*)&dst[(size_t)(bb * NH + h) * BHSTRIDE +
                              (size_t)ns * HD + d0] = pk2;
            }
        }
    } else {
        // V transposed: vT[(b*NH+h)*BHSTRIDE + d*SEQN + n]
#pragma unroll
        for (int j = 0; j < 4; j++) {
            const int o  = n0 + wn * 64 + j * 16 + ln;
            const float bval = bias[o];
            const int h = o >> 6, d = o & 63;
#pragma unroll
            for (int i = 0; i < 4; i++) {
                const int mg = m0 + wm * 64 + i * 16 + quad * 4;
                const int b  = mg >> 11;
                const int ns = mg & 2047;
                uint2 pk2;
                pk2.x = cvtpk(acc[i][j][0] + bval, acc[i][j][1] + bval);
                pk2.y = cvtpk(acc[i][j][2] + bval, acc[i][j][3] + bval);
                *(uint2*)&vT[(size_t)(b * NH + h) * BHSTRIDE +
                             (size_t)d * SEQN + ns] = pk2;
            }
        }
    }
}

// =====================================================================
// Kernel 2: distance-biased attention — round-5/8 version VERBATIM
// (measured best 104 us).  dbuf K/V, 1 barrier/kt, hoisted L loads,
// setprio, XCD-locality remap.  Deeper L-pipelining regresses via
// scratch spill (rounds 6/7); do not re-add.
// grid = (16,16,4); 4 waves; LDS 36 KB.
// =====================================================================
__global__ __launch_bounds__(256, 4) void attn(
        ushort* q,                     // aliased in/out (no restrict)
        const ushort* __restrict__ k,
        const ushort* __restrict__ vT,
        const float* __restrict__ Lp) {
    __shared__ short Ks[2][64 * 72];   // [buf][kv][d]
    __shared__ short Vs[2][64 * 72];   // [buf][d][kv]
    const int t = threadIdx.x, lane = t & 63, wave = t >> 6;
    const int lo = lane & 31, hi = lane >> 5;
    // ---- XCD-locality remap ----
    const int wid  = blockIdx.x + (blockIdx.y << 4) + (blockIdx.z << 8);
    const int xcd  = wid & 7;
    const int slot = wid >> 3;            // 0..127
    const int bh   = xcd * 8 + (slot >> 4);   // 0..63: 8 bh per XCD
    const int qx   = slot & 15;
    const int qw0 = qx * 128 + wave * 32;   // this wave's 32 q-rows

    ushort* qp = q + (size_t)bh * BHSTRIDE;
    const ushort* kp = k  + (size_t)bh * BHSTRIDE;
    const ushort* vp = vT + (size_t)bh * BHSTRIDE;
    // permuted L: lane's base covers (qt = qw0>>5, lo); step = kv4*32 float4s
    const float4* Lp4 = (const float4*)Lp + ((size_t)(qw0 >> 5) * 512) * 32 + lo;

    // staging coords: thread t covers row sr, 16-short chunk sc
    const int sr = t >> 2;           // 0..63
    const int sc = (t & 3) * 16;     // 0,16,32,48

    // Q B-fragments: B[j=q=lo][k=d: kk*16 + hi*8 + c]
    bf16x8 qf[4];
#pragma unroll
    for (int kk = 0; kk < 4; kk++)
        qf[kk] = *(const bf16x8*)(qp + (size_t)(qw0 + lo) * HD + kk * 16 + hi * 8);

    f32x16 O[2];                     // O^T accum: rows d, col q=lo
#pragma unroll
    for (int dt = 0; dt < 2; dt++)
#pragma unroll
        for (int i = 0; i < 16; i++) O[dt][i] = 0.f;
    float lsum = 0.f;

    // ---- prologue: tile 0 -> buf0, tile 1 -> regs ----
    uint4 krg0 = *(const uint4*)(kp + (size_t)sr * HD + sc);
    uint4 krg1 = *(const uint4*)(kp + (size_t)sr * HD + sc + 8);
    uint4 vrg0 = *(const uint4*)(vp + (size_t)sr * SEQN + sc);
    uint4 vrg1 = *(const uint4*)(vp + (size_t)sr * SEQN + sc + 8);
    *(uint4*)&Ks[0][sr * 72 + sc]     = krg0;
    *(uint4*)&Ks[0][sr * 72 + sc + 8] = krg1;
    *(uint4*)&Vs[0][sr * 72 + sc]     = vrg0;
    *(uint4*)&Vs[0][sr * 72 + sc + 8] = vrg1;
    krg0 = *(const uint4*)(kp + (size_t)(64 + sr) * HD + sc);
    krg1 = *(const uint4*)(kp + (size_t)(64 + sr) * HD + sc + 8);
    vrg0 = *(const uint4*)(vp + (size_t)sr * SEQN + 64 + sc);
    vrg1 = *(const uint4*)(vp + (size_t)sr * SEQN + 64 + sc + 8);

    for (int kt = 0; kt < 32; kt++) {
        const int kv0 = kt * 64;
        const int cb = kt & 1;       // compute buffer
        __syncthreads();             // buf[cb] visible; readers of buf[cb^1] done
        // ---- write tile kt+1 into alt buffer (overlaps others' compute) ----
        *(uint4*)&Ks[cb ^ 1][sr * 72 + sc]     = krg0;
        *(uint4*)&Ks[cb ^ 1][sr * 72 + sc + 8] = krg1;
        *(uint4*)&Vs[cb ^ 1][sr * 72 + sc]     = vrg0;
        *(uint4*)&Vs[cb ^ 1][sr * 72 + sc + 8] = vrg1;
        // ---- issue global loads for tile kt+2 (wrap: harmless) ----
        const int kvn = (kv0 + 128) & 2047;
        krg0 = *(const uint4*)(kp + (size_t)(kvn + sr) * HD + sc);
        krg1 = *(const uint4*)(kp + (size_t)(kvn + sr) * HD + sc + 8);
        vrg0 = *(const uint4*)(vp + (size_t)sr * SEQN + kvn + sc);
        vrg1 = *(const uint4*)(vp + (size_t)sr * SEQN + kvn + sc + 8);
        // ---- hoisted L loads for THIS tile (cover: ds_reads + QK^T) ----
        float4 lv2[2][4];
#pragma unroll
        for (int s = 0; s < 2; s++)
#pragma unroll
            for (int n = 0; n < 4; n++)
                lv2[s][n] = Lp4[((kv0 >> 2) + s * 8 + hi + 2 * n) * 32];

#pragma unroll
        for (int s = 0; s < 2; s++) {
            // ---- S^T = K Q^T for kv-subtile s (32 rows) ----
            f32x16 z;
#pragma unroll
            for (int i = 0; i < 16; i++) z[i] = 0.f;
            __builtin_amdgcn_s_setprio(1);
#pragma unroll
            for (int kk = 0; kk < 4; kk++) {
                bf16x8 kf = *(bf16x8*)&Ks[cb][(s * 32 + lo) * 72 + kk * 16 + hi * 8];
                z = __builtin_amdgcn_mfma_f32_32x32x16_bf16(kf, qf[kk], z, 0, 0, 0);
            }
            __builtin_amdgcn_s_setprio(0);
            // ---- p = exp2(s*log2e + L); lane-local row sum ----
            // z[n*4+m] <-> kv = kv0 + s*32 + 4*hi + 8*n + m
            float p[16];
#pragma unroll
            for (int n = 0; n < 4; n++) {
#pragma unroll
                for (int m = 0; m < 4; m++) {
                    float pv = EXP2(fmaf(z[n * 4 + m], 1.44269504f,
                                         ((const float*)&lv2[s][n])[m]));
                    lsum += pv;
                    p[n * 4 + m] = pv;
                }
            }
            // ---- pack to PV B-fragments in-register + PV MFMA ----
#pragma unroll
            for (int kl = 0; kl < 2; kl++) {
                unsigned a0 = cvtpk(p[kl * 8 + 0], p[kl * 8 + 1]);
                unsigned b0 = cvtpk(p[kl * 8 + 4], p[kl * 8 + 5]);
                plswap(a0, b0);          // a0 -> word0, b0 -> word2
                unsigned a1 = cvtpk(p[kl * 8 + 2], p[kl * 8 + 3]);
                unsigned b1 = cvtpk(p[kl * 8 + 6], p[kl * 8 + 7]);
                plswap(a1, b1);          // a1 -> word1, b1 -> word3
                union { bf16x8 v; unsigned u[4]; } pf;
                pf.u[0] = a0; pf.u[1] = a1; pf.u[2] = b0; pf.u[3] = b1;
                const int kvk = s * 2 + kl;      // 16-kv block within tile
                __builtin_amdgcn_s_setprio(1);
#pragma unroll
                for (int dt = 0; dt < 2; dt++) {
                    bf16x8 vf = *(bf16x8*)&Vs[cb][(dt * 32 + lo) * 72 +
                                                  kvk * 16 + hi * 8];
                    O[dt] = __builtin_amdgcn_mfma_f32_32x32x16_bf16(
                                vf, pf.v, O[dt], 0, 0, 0);
                }
                __builtin_amdgcn_s_setprio(0);
            }
        }
    }

    // denominator: hi halves hold kv-disjoint partial sums for q=lo
    float tot = lsum + __shfl_xor(lsum, 32);
    const float inv = 1.0f / tot;
    // store O^T: d = dt*32 + 4*hi + 8*n + m, q = qw0+lo; pack 4 -> uint2
#pragma unroll
    for (int dt = 0; dt < 2; dt++)
#pragma unroll
        for (int n = 0; n < 4; n++) {
            uint2 pk2;
            pk2.x = cvtpk(O[dt][n * 4 + 0] * inv, O[dt][n * 4 + 1] * inv);
            pk2.y = cvtpk(O[dt][n * 4 + 2] * inv, O[dt][n * 4 + 3] * inv);
            *(uint2*)(qp + (size_t)(qw0 + lo) * HD + dt * 32 + hi * 4 + n * 8)
                = pk2;
        }
}

// =====================================================================
// Kernel 3: output projection -> d_out.  grid = (M/128, 8), BK=32,
// tile-dbuf 2-phase pipeline (same structure as gemm_qkv).
// =====================================================================
__global__ __launch_bounds__(256) void gemm_out(
        const ushort* __restrict__ ao, const ushort* __restrict__ Wob,
        const float* __restrict__ bias, float* __restrict__ out) {
    __shared__ ushort As[2][LDSZ];
    __shared__ ushort Bs[2][LDSZ];
    const int m0 = blockIdx.x * 128;
    const int n0 = blockIdx.y * 128;
    const int t = threadIdx.x, lane = t & 63, wave = t >> 6;
    const int ln = lane & 15, quad = lane >> 4;
    const int wm = wave & 1, wn = wave >> 1;

    const int e0 = wave * 128 + lane;
    const int e1 = e0 + 64;
    const int bb = m0 >> 11;
    const int nbase = m0 & 2047;
    const ushort* gA0 = ao + ((size_t)bb << 21) +
                        (size_t)(nbase + (e0 >> 2)) * 64 + (e0 & 3) * 8;
    const ushort* gA1 = ao + ((size_t)bb << 21) +
                        (size_t)(nbase + (e1 >> 2)) * 64 + (e1 & 3) * 8;
    const ushort* gB0 = Wob + (size_t)(n0 + (e0 >> 2)) * 1024 + (e0 & 3) * 8;
    const ushort* gB1 = Wob + (size_t)(n0 + (e1 >> 2)) * 1024 + (e1 & 3) * 8;
    const int lofs = wave * 1024;

    f32x4 acc[4][4];
#pragma unroll
    for (int i = 0; i < 4; i++)
#pragma unroll
        for (int j = 0; j < 4; j++) acc[i][j] = (f32x4){0.f, 0.f, 0.f, 0.f};

    // A chunk offset within [B,H,N,D] for K-position k0: head = k0>>6, sub = k0&32
    // (k0 multiple of 32)
    // ---- prologue: stage tile 0 ----
    gload16(gA0, &As[0][lofs]); gload16(gA1, &As[0][lofs + 512]);
    gload16(gB0, &Bs[0][lofs]); gload16(gB1, &Bs[0][lofs + 512]);
    __syncthreads();

#pragma unroll 2
    for (int kt = 0; kt < 32; kt++) {
        const int cur = kt & 1;
        if (kt < 31) {
            const int k0n = kt * 32 + 32;
            const size_t aoffn = ((size_t)(k0n >> 6) << 17) + (k0n & 32);
            gload16(gA0 + aoffn, &As[cur ^ 1][lofs]);
            gload16(gA1 + aoffn, &As[cur ^ 1][lofs + 512]);
            gload16(gB0 + k0n,   &Bs[cur ^ 1][lofs]);
            gload16(gB1 + k0n,   &Bs[cur ^ 1][lofs + 512]);
        }
        bf16x8 af[4], bfr[4];
#pragma unroll
        for (int i = 0; i < 4; i++)
            af[i]  = *(bf16x8*)&As[cur][(wm * 64 + i * 16 + ln) * 32 + quad * 8];
#pragma unroll
        for (int j = 0; j < 4; j++)
            bfr[j] = *(bf16x8*)&Bs[cur][(wn * 64 + j * 16 + ln) * 32 + quad * 8];
#pragma unroll
        for (int i = 0; i < 4; i++)
#pragma unroll
            for (int j = 0; j < 4; j++)
                acc[i][j] = __builtin_amdgcn_mfma_f32_16x16x32_bf16(
                                af[i], bfr[j], acc[i][j], 0, 0, 0);
        __syncthreads();
    }

#pragma unroll
    for (int j = 0; j < 4; j++) {
        const int o = n0 + wn * 64 + j * 16 + ln;
        const float bval = bias[o];
#pragma unroll
        for (int i = 0; i < 4; i++) {
            const int mg = m0 + wm * 64 + i * 16 + quad * 4;
#pragma unroll
            for (int r = 0; r < 4; r++)
                out[(size_t)(mg + r) * EMB + o] = acc[i][j][r] + bval;
        }
    }
}

// =====================================================================
extern "C" void kernel_launch(void* const* d_in, const int* in_sizes, int n_in,
                              void* d_out, int out_size, void* d_ws, size_t ws_size,
                              hipStream_t stream) {
    const float* x    = (const float*)d_in[0];
    const float* dist = (const float*)d_in[1];
    const float* Wq   = (const float*)d_in[2];
    const float* bq   = (const float*)d_in[3];
    const float* Wk   = (const float*)d_in[4];
    const float* bk   = (const float*)d_in[5];
    const float* Wv   = (const float*)d_in[6];
    const float* bv   = (const float*)d_in[7];
    const float* Wo   = (const float*)d_in[8];
    const float* bo   = (const float*)d_in[9];
    const float* dw   = (const float*)d_in[10];
    const float* db   = (const float*)d_in[11];

    const size_t PLANE = (size_t)8192 * 1024;   // elems per [M,C] bf16 buffer
    ushort* qb = (ushort*)d_ws;                 // [B,H,N,D] bf16, later attn out
    ushort* kb = qb + PLANE;                    // [B,H,N,D] bf16
    ushort* xb = kb + PLANE;                    // x as bf16 [8192][1024]
    ushort* Wb = xb + PLANE;                    // [Wq;Wk;Wv;Wo] bf16
    // d_out (33.55 MB fp32) as scratch before gemm_out:
    ushort* vT = (ushort*)d_out;                // [B,H,D,N] bf16 (16.78 MB)
    float*  Lf = (float*)(vT + PLANE);          // permuted f32 L table (16.78 MB)

    dim3 blk(256);
    conv_x       <<<dim3(4096),      blk, 0, stream>>>(x, xb);
    conv_w4      <<<dim3(512, 4),    blk, 0, stream>>>(Wq, Wk, Wv, Wo, Wb);
    conv_Lp      <<<dim3(4096),      blk, 0, stream>>>(dist, dw, db, Lf);
    gemm_qkv     <<<dim3(64, 24),    blk, 0, stream>>>(xb, Wb, bq, bk, bv,
                                                       qb, kb, vT);
    attn         <<<dim3(16, 16, 4), blk, 0, stream>>>(qb, kb, vT, Lf);
    gemm_out     <<<dim3(64, 8),     blk, 0, stream>>>(qb, Wb + 3 * (size_t)(1 << 20),
                                                       bo, (float*)d_out);
}

// Round 10
// 311.253 us; speedup vs baseline: 1.0453x; 1.0453x over previous
//
#include <hip/hip_runtime.h>
#include <stdint.h>

typedef unsigned short ushort;
typedef __attribute__((ext_vector_type(8))) short bf16x8;
typedef __attribute__((ext_vector_type(4))) float f32x4;
typedef __attribute__((ext_vector_type(16))) float f32x16;

// ---- bf16 helpers (bit-level) ----
__device__ __forceinline__ float b2f(ushort u) {
    return __uint_as_float(((unsigned)u) << 16);
}
__device__ __forceinline__ ushort f2b(float f) {
    unsigned u = __float_as_uint(f);
    u += 0x7fff + ((u >> 16) & 1);   // round-to-nearest-even
    return (ushort)(u >> 16);
}

// exp2 (native v_exp_f32), compile-safe
#if __has_builtin(__builtin_amdgcn_exp2f)
#define EXP2(x) __builtin_amdgcn_exp2f(x)
#else
#define EXP2(x) __expf((x) * 0.69314718056f)
#endif

// v_cvt_pk_bf16_f32: pack 2 f32 -> 2 bf16 in one u32 (RNE)
__device__ __forceinline__ unsigned cvtpk(float a, float b) {
    unsigned r;
    asm("v_cvt_pk_bf16_f32 %0, %1, %2" : "=v"(r) : "v"(a), "v"(b));
    return r;
}

// v_permlane32_swap_b32: exchange halves across lane<32 / lane>=32.
__device__ __forceinline__ void plswap(unsigned &a, unsigned &b) {
#if __has_builtin(__builtin_amdgcn_permlane32_swap)
    auto r = __builtin_amdgcn_permlane32_swap(a, b, 0, 0);
    a = (unsigned)r[0]; b = (unsigned)r[1];
#else
    asm volatile("v_permlane32_swap_b32 %0, %1" : "+v"(a), "+v"(b));
#endif
}

// Problem constants: B=4, N=2048, C=1024, H=16, D=64, M = B*N = 8192
#define SEQN 2048
#define EMB  1024
#define NH   16
#define HD   64
#define BHSTRIDE (SEQN * HD)   // 131072 elems per (b,h) plane

// async global->LDS, 16B per lane; LDS dest = wave-uniform base + lane*16
__device__ __forceinline__ void gload16(const ushort* g, ushort* l) {
    __builtin_amdgcn_global_load_lds(
        (const __attribute__((address_space(1))) unsigned int*)g,
        (__attribute__((address_space(3))) unsigned int*)l, 16, 0, 0);
}

// =====================================================================
// Kernel A (fused): all fp32->bf16 conversions + permuted L table in
// ONE dispatch (saves 2 launches + 2 kernel tails vs rounds 5-9).
// Block-uniform branch on blockIdx.x range; per-element math identical
// to the previous conv_x / conv_w4 / conv_Lp kernels.
//   blocks [0,4096):      x  fp32 -> xb bf16          (8 elems/thread)
//   blocks [4096,6144):   Wq|Wk|Wv|Wo fp32 -> Wb bf16 (512 blocks each)
//   blocks [6144,10240):  dist -> permuted log2-bias table Lp (f32)
// =====================================================================
__global__ __launch_bounds__(256) void conv_all(
        const float* __restrict__ x,
        const float* __restrict__ W0, const float* __restrict__ W1,
        const float* __restrict__ W2, const float* __restrict__ W3,
        const float* __restrict__ dist, const float* __restrict__ dw,
        const float* __restrict__ db,
        ushort* __restrict__ xb, ushort* __restrict__ Wb,
        float* __restrict__ Lp) {
    const int bx = blockIdx.x;
    if (bx < 4096) {
        // ---- x conversion ----
        const size_t i = (size_t)bx * 256 + threadIdx.x;
        float4 a = ((const float4*)x)[2 * i];
        float4 b = ((const float4*)x)[2 * i + 1];
        ushort pk[8] = {f2b(a.x), f2b(a.y), f2b(a.z), f2b(a.w),
                        f2b(b.x), f2b(b.y), f2b(b.z), f2b(b.w)};
        ((uint4*)xb)[i] = *(uint4*)pk;
    } else if (bx < 6144) {
        // ---- weight conversion: 4 matrices x 512 blocks ----
        const int wb = bx - 4096;
        const int wsel = wb >> 9;            // 0..3
        const float* s = (wsel == 0) ? W0 : (wsel == 1) ? W1
                       : (wsel == 2) ? W2 : W3;
        ushort* dst = Wb + ((size_t)wsel << 20);
        const size_t i = (size_t)(wb & 511) * 256 + threadIdx.x;
        float4 a = ((const float4*)s)[2 * i];
        float4 b = ((const float4*)s)[2 * i + 1];
        ushort pk[8] = {f2b(a.x), f2b(a.y), f2b(a.z), f2b(a.w),
                        f2b(b.x), f2b(b.y), f2b(b.z), f2b(b.w)};
        ((uint4*)dst)[i] = *(uint4*)pk;
    } else {
        // ---- permuted log2-domain bias table ----
        // Lp[qt][kv4][lo] (float4 over kv&3), qt = q>>5, lo = q&31.
        const float c1 = dw[0] * 1.44269504f, c2 = db[0] * 1.44269504f;
        const size_t gid = (size_t)(bx - 6144) * 256 + threadIdx.x;
        const int lo  = (int)(gid & 31);
        const int kv4 = (int)((gid >> 5) & 511);
        const int qt  = (int)(gid >> 14);
        const int q   = qt * 32 + lo;
        float4 d = *(const float4*)(dist + (size_t)q * SEQN + kv4 * 4);
        float4 o = {fmaf(d.x, c1, c2), fmaf(d.y, c1, c2),
                    fmaf(d.z, c1, c2), fmaf(d.w, c1, c2)};
        ((float4*)Lp)[gid] = o;
    }
}

// =====================================================================
// GEMM pieces: 128x128 tile, BK=64 as TWO BK=32 sub-buffers (keeps the
// conflict-free 64B row stride under global_load_lds; rule #21).  One
// barrier pair per 64-K (round-5 structure, measured best; round-9's
// "pipelined" variant regressed: __syncthreads drains vmcnt so the
// prefetch can't stay in flight, and it doubled barrier frequency).
// =====================================================================
#define LDSZ (128 * 32)   // shorts per sub-buffer

// =====================================================================
// Kernel 1: fused QKV projection.  grid = (M/128, 3*8)
// =====================================================================
__global__ __launch_bounds__(256) void gemm_qkv(
        const ushort* __restrict__ xb, const ushort* __restrict__ Wb,
        const float* __restrict__ bq, const float* __restrict__ bk,
        const float* __restrict__ bv,
        ushort* __restrict__ qb, ushort* __restrict__ kb,
        ushort* __restrict__ vT) {
    __shared__ ushort As[2][LDSZ];
    __shared__ ushort Bs[2][LDSZ];
    const int m0   = blockIdx.x * 128;
    const int nt   = blockIdx.y;           // 0..23
    const int wsel = nt >> 3;
    const int n0   = (nt & 7) * 128;
    const ushort* W    = Wb + ((size_t)wsel << 20);
    const float* bias  = (wsel == 0) ? bq : (wsel == 1) ? bk : bv;

    const int t = threadIdx.x, lane = t & 63, wave = t >> 6;
    const int ln = lane & 15, quad = lane >> 4;
    const int wm = wave & 1, wn = wave >> 1;

    const int e0 = wave * 128 + lane;
    const int e1 = e0 + 64;
    const ushort* gA0 = xb + (size_t)(m0 + (e0 >> 2)) * 1024 + (e0 & 3) * 8;
    const ushort* gA1 = xb + (size_t)(m0 + (e1 >> 2)) * 1024 + (e1 & 3) * 8;
    const ushort* gB0 = W  + (size_t)(n0 + (e0 >> 2)) * 1024 + (e0 & 3) * 8;
    const ushort* gB1 = W  + (size_t)(n0 + (e1 >> 2)) * 1024 + (e1 & 3) * 8;
    ushort* lA0a = &As[0][wave * 1024]; ushort* lA0b = lA0a + 512;
    ushort* lA1a = &As[1][wave * 1024]; ushort* lA1b = lA1a + 512;
    ushort* lB0a = &Bs[0][wave * 1024]; ushort* lB0b = lB0a + 512;
    ushort* lB1a = &Bs[1][wave * 1024]; ushort* lB1b = lB1a + 512;

    f32x4 acc[4][4];
#pragma unroll
    for (int i = 0; i < 4; i++)
#pragma unroll
        for (int j = 0; j < 4; j++) acc[i][j] = (f32x4){0.f, 0.f, 0.f, 0.f};

    for (int k0 = 0; k0 < 1024; k0 += 64) {
        __syncthreads();
        gload16(gA0 + k0,      lA0a); gload16(gA1 + k0,      lA0b);
        gload16(gB0 + k0,      lB0a); gload16(gB1 + k0,      lB0b);
        gload16(gA0 + k0 + 32, lA1a); gload16(gA1 + k0 + 32, lA1b);
        gload16(gB0 + k0 + 32, lB1a); gload16(gB1 + k0 + 32, lB1b);
        __syncthreads();
#pragma unroll
        for (int kk2 = 0; kk2 < 2; kk2++) {
            bf16x8 af[4], bfr[4];
#pragma unroll
            for (int i = 0; i < 4; i++)
                af[i]  = *(bf16x8*)&As[kk2][(wm * 64 + i * 16 + ln) * 32 + quad * 8];
#pragma unroll
            for (int j = 0; j < 4; j++)
                bfr[j] = *(bf16x8*)&Bs[kk2][(wn * 64 + j * 16 + ln) * 32 + quad * 8];
#pragma unroll
            for (int i = 0; i < 4; i++)
#pragma unroll
                for (int j = 0; j < 4; j++)
                    acc[i][j] = __builtin_amdgcn_mfma_f32_16x16x32_bf16(
                                    af[i], bfr[j], acc[i][j], 0, 0, 0);
        }
    }

    if (wsel < 2) {
        ushort* dst = (wsel == 0) ? qb : kb;
        const float scale = (wsel == 0) ? 0.125f : 1.0f;   // q pre-scaled
#pragma unroll
        for (int j = 0; j < 4; j++) {
            const int o  = n0 + wn * 64 + j * 16 + ln;
            const float bval = bias[o];
            const int h = o >> 6, d = o & 63;
#pragma unroll
            for (int i = 0; i < 4; i++) {
                const int mg = m0 + wm * 64 + i * 16 + quad * 4;
#pragma unroll
                for (int r = 0; r < 4; r++) {
                    const int m  = mg + r;
                    const int b  = m >> 11;
                    const int ns = m & 2047;
                    dst[(size_t)(b * NH + h) * BHSTRIDE + (size_t)ns * HD + d] =
                        f2b((acc[i][j][r] + bval) * scale);
                }
            }
        }
    } else {
        // V transposed: vT[(b*NH+h)*BHSTRIDE + d*SEQN + n]
#pragma unroll
        for (int j = 0; j < 4; j++) {
            const int o  = n0 + wn * 64 + j * 16 + ln;
            const float bval = bias[o];
            const int h = o >> 6, d = o & 63;
#pragma unroll
            for (int i = 0; i < 4; i++) {
                const int mg = m0 + wm * 64 + i * 16 + quad * 4;
                const int b  = mg >> 11;
                const int ns = mg & 2047;
                ushort pk[4];
#pragma unroll
                for (int r = 0; r < 4; r++) pk[r] = f2b(acc[i][j][r] + bval);
                *(uint2*)&vT[(size_t)(b * NH + h) * BHSTRIDE +
                             (size_t)d * SEQN + ns] = *(uint2*)&pk[0];
            }
        }
    }
}

// =====================================================================
// Kernel 2: distance-biased attention — round-5 version VERBATIM
// (measured best ~104-106 us).  dbuf K/V, 1 barrier/kt, hoisted L
// loads, setprio, XCD-locality remap.  Deeper L-pipelining regresses
// via scratch spill (rounds 6/7: VGPR allocator pins 64); do not re-add.
// grid = (16,16,4); 4 waves; LDS 36 KB.
// =====================================================================
__global__ __launch_bounds__(256, 4) void attn(
        ushort* q,                     // aliased in/out (no restrict)
        const ushort* __restrict__ k,
        const ushort* __restrict__ vT,
        const float* __restrict__ Lp) {
    __shared__ short Ks[2][64 * 72];   // [buf][kv][d]
    __shared__ short Vs[2][64 * 72];   // [buf][d][kv]
    const int t = threadIdx.x, lane = t & 63, wave = t >> 6;
    const int lo = lane & 31, hi = lane >> 5;
    // ---- XCD-locality remap ----
    const int wid  = blockIdx.x + (blockIdx.y << 4) + (blockIdx.z << 8);
    const int xcd  = wid & 7;
    const int slot = wid >> 3;            // 0..127
    const int bh   = xcd * 8 + (slot >> 4);   // 0..63: 8 bh per XCD
    const int qx   = slot & 15;
    const int qw0 = qx * 128 + wave * 32;   // this wave's 32 q-rows

    ushort* qp = q + (size_t)bh * BHSTRIDE;
    const ushort* kp = k  + (size_t)bh * BHSTRIDE;
    const ushort* vp = vT + (size_t)bh * BHSTRIDE;
    // permuted L: lane's base covers (qt = qw0>>5, lo); step = kv4*32 float4s
    const float4* Lp4 = (const float4*)Lp + ((size_t)(qw0 >> 5) * 512) * 32 + lo;

    // staging coords: thread t covers row sr, 16-short chunk sc
    const int sr = t >> 2;           // 0..63
    const int sc = (t & 3) * 16;     // 0,16,32,48

    // Q B-fragments: B[j=q=lo][k=d: kk*16 + hi*8 + c]
    bf16x8 qf[4];
#pragma unroll
    for (int kk = 0; kk < 4; kk++)
        qf[kk] = *(const bf16x8*)(qp + (size_t)(qw0 + lo) * HD + kk * 16 + hi * 8);

    f32x16 O[2];                     // O^T accum: rows d, col q=lo
#pragma unroll
    for (int dt = 0; dt < 2; dt++)
#pragma unroll
        for (int i = 0; i < 16; i++) O[dt][i] = 0.f;
    float lsum = 0.f;

    // ---- prologue: tile 0 -> buf0, tile 1 -> regs ----
    uint4 krg0 = *(const uint4*)(kp + (size_t)sr * HD + sc);
    uint4 krg1 = *(const uint4*)(kp + (size_t)sr * HD + sc + 8);
    uint4 vrg0 = *(const uint4*)(vp + (size_t)sr * SEQN + sc);
    uint4 vrg1 = *(const uint4*)(vp + (size_t)sr * SEQN + sc + 8);
    *(uint4*)&Ks[0][sr * 72 + sc]     = krg0;
    *(uint4*)&Ks[0][sr * 72 + sc + 8] = krg1;
    *(uint4*)&Vs[0][sr * 72 + sc]     = vrg0;
    *(uint4*)&Vs[0][sr * 72 + sc + 8] = vrg1;
    krg0 = *(const uint4*)(kp + (size_t)(64 + sr) * HD + sc);
    krg1 = *(const uint4*)(kp + (size_t)(64 + sr) * HD + sc + 8);
    vrg0 = *(const uint4*)(vp + (size_t)sr * SEQN + 64 + sc);
    vrg1 = *(const uint4*)(vp + (size_t)sr * SEQN + 64 + sc + 8);

    for (int kt = 0; kt < 32; kt++) {
        const int kv0 = kt * 64;
        const int cb = kt & 1;       // compute buffer
        __syncthreads();             // buf[cb] visible; readers of buf[cb^1] done
        // ---- write tile kt+1 into alt buffer (overlaps others' compute) ----
        *(uint4*)&Ks[cb ^ 1][sr * 72 + sc]     = krg0;
        *(uint4*)&Ks[cb ^ 1][sr * 72 + sc + 8] = krg1;
        *(uint4*)&Vs[cb ^ 1][sr * 72 + sc]     = vrg0;
        *(uint4*)&Vs[cb ^ 1][sr * 72 + sc + 8] = vrg1;
        // ---- issue global loads for tile kt+2 (wrap: harmless) ----
        const int kvn = (kv0 + 128) & 2047;
        krg0 = *(const uint4*)(kp + (size_t)(kvn + sr) * HD + sc);
        krg1 = *(const uint4*)(kp + (size_t)(kvn + sr) * HD + sc + 8);
        vrg0 = *(const uint4*)(vp + (size_t)sr * SEQN + kvn + sc);
        vrg1 = *(const uint4*)(vp + (size_t)sr * SEQN + kvn + sc + 8);
        // ---- hoisted L loads for THIS tile (cover: ds_reads + QK^T) ----
        float4 lv2[2][4];
#pragma unroll
        for (int s = 0; s < 2; s++)
#pragma unroll
            for (int n = 0; n < 4; n++)
                lv2[s][n] = Lp4[((kv0 >> 2) + s * 8 + hi + 2 * n) * 32];

#pragma unroll
        for (int s = 0; s < 2; s++) {
            // ---- S^T = K Q^T for kv-subtile s (32 rows) ----
            f32x16 z;
#pragma unroll
            for (int i = 0; i < 16; i++) z[i] = 0.f;
            __builtin_amdgcn_s_setprio(1);
#pragma unroll
            for (int kk = 0; kk < 4; kk++) {
                bf16x8 kf = *(bf16x8*)&Ks[cb][(s * 32 + lo) * 72 + kk * 16 + hi * 8];
                z = __builtin_amdgcn_mfma_f32_32x32x16_bf16(kf, qf[kk], z, 0, 0, 0);
            }
            __builtin_amdgcn_s_setprio(0);
            // ---- p = exp2(s*log2e + L); lane-local row sum ----
            // z[n*4+m] <-> kv = kv0 + s*32 + 4*hi + 8*n + m
            float p[16];
#pragma unroll
            for (int n = 0; n < 4; n++) {
#pragma unroll
                for (int m = 0; m < 4; m++) {
                    float pv = EXP2(fmaf(z[n * 4 + m], 1.44269504f,
                                         ((const float*)&lv2[s][n])[m]));
                    lsum += pv;
                    p[n * 4 + m] = pv;
                }
            }
            // ---- pack to PV B-fragments in-register + PV MFMA ----
#pragma unroll
            for (int kl = 0; kl < 2; kl++) {
                unsigned a0 = cvtpk(p[kl * 8 + 0], p[kl * 8 + 1]);
                unsigned b0 = cvtpk(p[kl * 8 + 4], p[kl * 8 + 5]);
                plswap(a0, b0);          // a0 -> word0, b0 -> word2
                unsigned a1 = cvtpk(p[kl * 8 + 2], p[kl * 8 + 3]);
                unsigned b1 = cvtpk(p[kl * 8 + 6], p[kl * 8 + 7]);
                plswap(a1, b1);          // a1 -> word1, b1 -> word3
                union { bf16x8 v; unsigned u[4]; } pf;
                pf.u[0] = a0; pf.u[1] = a1; pf.u[2] = b0; pf.u[3] = b1;
                const int kvk = s * 2 + kl;      // 16-kv block within tile
                __builtin_amdgcn_s_setprio(1);
#pragma unroll
                for (int dt = 0; dt < 2; dt++) {
                    bf16x8 vf = *(bf16x8*)&Vs[cb][(dt * 32 + lo) * 72 +
                                                  kvk * 16 + hi * 8];
                    O[dt] = __builtin_amdgcn_mfma_f32_32x32x16_bf16(
                                vf, pf.v, O[dt], 0, 0, 0);
                }
                __builtin_amdgcn_s_setprio(0);
            }
        }
    }

    // denominator: hi halves hold kv-disjoint partial sums for q=lo
    float tot = lsum + __shfl_xor(lsum, 32);
    const float inv = 1.0f / tot;
    // store O^T: d = dt*32 + 4*hi + 8*n + m, q = qw0+lo; pack 4 -> uint2
#pragma unroll
    for (int dt = 0; dt < 2; dt++)
#pragma unroll
        for (int n = 0; n < 4; n++) {
            uint2 pk2;
            pk2.x = cvtpk(O[dt][n * 4 + 0] * inv, O[dt][n * 4 + 1] * inv);
            pk2.y = cvtpk(O[dt][n * 4 + 2] * inv, O[dt][n * 4 + 3] * inv);
            *(uint2*)(qp + (size_t)(qw0 + lo) * HD + dt * 32 + hi * 4 + n * 8)
                = pk2;
        }
}

// =====================================================================
// Kernel 3: output projection -> d_out.  grid = (M/128, 8), BK=64
// (round-5 structure verbatim).
// =====================================================================
__global__ __launch_bounds__(256) void gemm_out(
        const ushort* __restrict__ ao, const ushort* __restrict__ Wob,
        const float* __restrict__ bias, float* __restrict__ out) {
    __shared__ ushort As[2][LDSZ];
    __shared__ ushort Bs[2][LDSZ];
    const int m0 = blockIdx.x * 128;
    const int n0 = blockIdx.y * 128;
    const int t = threadIdx.x, lane = t & 63, wave = t >> 6;
    const int ln = lane & 15, quad = lane >> 4;
    const int wm = wave & 1, wn = wave >> 1;

    const int e0 = wave * 128 + lane;
    const int e1 = e0 + 64;
    const int bb = m0 >> 11;
    const int nbase = m0 & 2047;
    const ushort* gA0 = ao + ((size_t)bb << 21) +
                        (size_t)(nbase + (e0 >> 2)) * 64 + (e0 & 3) * 8;
    const ushort* gA1 = ao + ((size_t)bb << 21) +
                        (size_t)(nbase + (e1 >> 2)) * 64 + (e1 & 3) * 8;
    const ushort* gB0 = Wob + (size_t)(n0 + (e0 >> 2)) * 1024 + (e0 & 3) * 8;
    const ushort* gB1 = Wob + (size_t)(n0 + (e1 >> 2)) * 1024 + (e1 & 3) * 8;
    ushort* lA0a = &As[0][wave * 1024]; ushort* lA0b = lA0a + 512;
    ushort* lA1a = &As[1][wave * 1024]; ushort* lA1b = lA1a + 512;
    ushort* lB0a = &Bs[0][wave * 1024]; ushort* lB0b = lB0a + 512;
    ushort* lB1a = &Bs[1][wave * 1024]; ushort* lB1b = lB1a + 512;

    f32x4 acc[4][4];
#pragma unroll
    for (int i = 0; i < 4; i++)
#pragma unroll
        for (int j = 0; j < 4; j++) acc[i][j] = (f32x4){0.f, 0.f, 0.f, 0.f};

    for (int k0 = 0; k0 < 1024; k0 += 64) {
        // A layout [B,H,N,D]: k0 multiple of 64 -> head h = k0>>6, d0 = 0/32
        const size_t aoff = ((size_t)(k0 >> 6) << 17);
        __syncthreads();
        gload16(gA0 + aoff,      lA0a); gload16(gA1 + aoff,      lA0b);
        gload16(gB0 + k0,        lB0a); gload16(gB1 + k0,        lB0b);
        gload16(gA0 + aoff + 32, lA1a); gload16(gA1 + aoff + 32, lA1b);
        gload16(gB0 + k0 + 32,   lB1a); gload16(gB1 + k0 + 32,   lB1b);
        __syncthreads();
#pragma unroll
        for (int kk2 = 0; kk2 < 2; kk2++) {
            bf16x8 af[4], bfr[4];
#pragma unroll
            for (int i = 0; i < 4; i++)
                af[i]  = *(bf16x8*)&As[kk2][(wm * 64 + i * 16 + ln) * 32 + quad * 8];
#pragma unroll
            for (int j = 0; j < 4; j++)
                bfr[j] = *(bf16x8*)&Bs[kk2][(wn * 64 + j * 16 + ln) * 32 + quad * 8];
#pragma unroll
            for (int i = 0; i < 4; i++)
#pragma unroll
                for (int j = 0; j < 4; j++)
                    acc[i][j] = __builtin_amdgcn_mfma_f32_16x16x32_bf16(
                                    af[i], bfr[j], acc[i][j], 0, 0, 0);
        }
    }

#pragma unroll
    for (int j = 0; j < 4; j++) {
        const int o = n0 + wn * 64 + j * 16 + ln;
        const float bval = bias[o];
#pragma unroll
        for (int i = 0; i < 4; i++) {
            const int mg = m0 + wm * 64 + i * 16 + quad * 4;
#pragma unroll
            for (int r = 0; r < 4; r++)
                out[(size_t)(mg + r) * EMB + o] = acc[i][j][r] + bval;
        }
    }
}

// =====================================================================
extern "C" void kernel_launch(void* const* d_in, const int* in_sizes, int n_in,
                              void* d_out, int out_size, void* d_ws, size_t ws_size,
                              hipStream_t stream) {
    const float* x    = (const float*)d_in[0];
    const float* dist = (const float*)d_in[1];
    const float* Wq   = (const float*)d_in[2];
    const float* bq   = (const float*)d_in[3];
    const float* Wk   = (const float*)d_in[4];
    const float* bk   = (const float*)d_in[5];
    const float* Wv   = (const float*)d_in[6];
    const float* bv   = (const float*)d_in[7];
    const float* Wo   = (const float*)d_in[8];
    const float* bo   = (const float*)d_in[9];
    const float* dw   = (const float*)d_in[10];
    const float* db   = (const float*)d_in[11];

    const size_t PLANE = (size_t)8192 * 1024;   // elems per [M,C] bf16 buffer
    ushort* qb = (ushort*)d_ws;                 // [B,H,N,D] bf16, later attn out
    ushort* kb = qb + PLANE;                    // [B,H,N,D] bf16
    ushort* xb = kb + PLANE;                    // x as bf16 [8192][1024]
    ushort* Wb = xb + PLANE;                    // [Wq;Wk;Wv;Wo] bf16
    // d_out (33.55 MB fp32) as scratch before gemm_out:
    ushort* vT = (ushort*)d_out;                // [B,H,D,N] bf16 (16.78 MB)
    float*  Lf = (float*)(vT + PLANE);          // permuted f32 L table (16.78 MB)

    dim3 blk(256);
    conv_all     <<<dim3(10240),     blk, 0, stream>>>(x, Wq, Wk, Wv, Wo,
                                                       dist, dw, db,
                                                       xb, Wb, Lf);
    gemm_qkv     <<<dim3(64, 24),    blk, 0, stream>>>(xb, Wb, bq, bk, bv,
                                                       qb, kb, vT);
    attn         <<<dim3(16, 16, 4), blk, 0, stream>>>(qb, kb, vT, Lf);
    gemm_out     <<<dim3(64, 8),     blk, 0, stream>>>(qb, Wb + 3 * (size_t)(1 << 20),
                                                       bo, (float*)d_out);
}

// Round 11
// 306.830 us; speedup vs baseline: 1.0604x; 1.0144x over previous
//
#include <hip/hip_runtime.h>
#include <stdint.h>

typedef unsigned short ushort;
typedef __attribute__((ext_vector_type(8))) short bf16x8;
typedef __attribute__((ext_vector_type(4))) float f32x4;
typedef __attribute__((ext_vector_type(16))) float f32x16;

// ---- bf16 helpers (bit-level) ----
__device__ __forceinline__ float b2f(ushort u) {
    return __uint_as_float(((unsigned)u) << 16);
}
__device__ __forceinline__ ushort f2b(float f) {
    unsigned u = __float_as_uint(f);
    u += 0x7fff + ((u >> 16) & 1);   // round-to-nearest-even
    return (ushort)(u >> 16);
}

// exp2 (native v_exp_f32), compile-safe
#if __has_builtin(__builtin_amdgcn_exp2f)
#define EXP2(x) __builtin_amdgcn_exp2f(x)
#else
#define EXP2(x) __expf((x) * 0.69314718056f)
#endif

// v_cvt_pk_bf16_f32: pack 2 f32 -> 2 bf16 in one u32 (RNE, same bits as f2b)
__device__ __forceinline__ unsigned cvtpk(float a, float b) {
    unsigned r;
    asm("v_cvt_pk_bf16_f32 %0, %1, %2" : "=v"(r) : "v"(a), "v"(b));
    return r;
}

// v_permlane32_swap_b32: exchange halves across lane<32 / lane>=32.
__device__ __forceinline__ void plswap(unsigned &a, unsigned &b) {
#if __has_builtin(__builtin_amdgcn_permlane32_swap)
    auto r = __builtin_amdgcn_permlane32_swap(a, b, 0, 0);
    a = (unsigned)r[0]; b = (unsigned)r[1];
#else
    asm volatile("v_permlane32_swap_b32 %0, %1" : "+v"(a), "+v"(b));
#endif
}

// Problem constants: B=4, N=2048, C=1024, H=16, D=64, M = B*N = 8192
#define SEQN 2048
#define EMB  1024
#define NH   16
#define HD   64
#define BHSTRIDE (SEQN * HD)   // 131072 elems per (b,h) plane

// async global->LDS, 16B per lane; LDS dest = wave-uniform base + lane*16
__device__ __forceinline__ void gload16(const ushort* g, ushort* l) {
    __builtin_amdgcn_global_load_lds(
        (const __attribute__((address_space(1))) unsigned int*)g,
        (__attribute__((address_space(3))) unsigned int*)l, 16, 0, 0);
}

// =====================================================================
// Kernel A (fused): all fp32->bf16 conversions + permuted L table in
// ONE dispatch.  Round-11: cvtpk packing (0.5 VALU/elem vs f2b's 3,
// identical RNE bits).
//   blocks [0,4096):      x  fp32 -> xb bf16          (8 elems/thread)
//   blocks [4096,6144):   Wq|Wk|Wv|Wo fp32 -> Wb bf16 (512 blocks each)
//   blocks [6144,10240):  dist -> permuted log2-bias table Lp (f32)
// =====================================================================
__global__ __launch_bounds__(256) void conv_all(
        const float* __restrict__ x,
        const float* __restrict__ W0, const float* __restrict__ W1,
        const float* __restrict__ W2, const float* __restrict__ W3,
        const float* __restrict__ dist, const float* __restrict__ dw,
        const float* __restrict__ db,
        ushort* __restrict__ xb, ushort* __restrict__ Wb,
        float* __restrict__ Lp) {
    const int bx = blockIdx.x;
    if (bx < 4096) {
        // ---- x conversion ----
        const size_t i = (size_t)bx * 256 + threadIdx.x;
        float4 a = ((const float4*)x)[2 * i];
        float4 b = ((const float4*)x)[2 * i + 1];
        uint4 pk;
        pk.x = cvtpk(a.x, a.y); pk.y = cvtpk(a.z, a.w);
        pk.z = cvtpk(b.x, b.y); pk.w = cvtpk(b.z, b.w);
        ((uint4*)xb)[i] = pk;
    } else if (bx < 6144) {
        // ---- weight conversion: 4 matrices x 512 blocks ----
        const int wb = bx - 4096;
        const int wsel = wb >> 9;            // 0..3
        const float* s = (wsel == 0) ? W0 : (wsel == 1) ? W1
                       : (wsel == 2) ? W2 : W3;
        ushort* dst = Wb + ((size_t)wsel << 20);
        const size_t i = (size_t)(wb & 511) * 256 + threadIdx.x;
        float4 a = ((const float4*)s)[2 * i];
        float4 b = ((const float4*)s)[2 * i + 1];
        uint4 pk;
        pk.x = cvtpk(a.x, a.y); pk.y = cvtpk(a.z, a.w);
        pk.z = cvtpk(b.x, b.y); pk.w = cvtpk(b.z, b.w);
        ((uint4*)dst)[i] = pk;
    } else {
        // ---- permuted log2-domain bias table ----
        // Lp[qt][kv4][lo] (float4 over kv&3), qt = q>>5, lo = q&31.
        const float c1 = dw[0] * 1.44269504f, c2 = db[0] * 1.44269504f;
        const size_t gid = (size_t)(bx - 6144) * 256 + threadIdx.x;
        const int lo  = (int)(gid & 31);
        const int kv4 = (int)((gid >> 5) & 511);
        const int qt  = (int)(gid >> 14);
        const int q   = qt * 32 + lo;
        float4 d = *(const float4*)(dist + (size_t)q * SEQN + kv4 * 4);
        float4 o = {fmaf(d.x, c1, c2), fmaf(d.y, c1, c2),
                    fmaf(d.z, c1, c2), fmaf(d.w, c1, c2)};
        ((float4*)Lp)[gid] = o;
    }
}

// =====================================================================
// GEMM pieces: 128x128 tile, BK=64 as TWO BK=32 sub-buffers (keeps the
// conflict-free 64B row stride under global_load_lds; rule #21).  One
// barrier pair per 64-K (round-5 structure, measured best; round-9's
// "pipelined" variant regressed: __syncthreads drains vmcnt so the
// prefetch can't stay in flight, and it doubled barrier frequency).
// =====================================================================
#define LDSZ (128 * 32)   // shorts per sub-buffer

// =====================================================================
// Kernel 1: fused QKV projection.  grid = (M/128, 3*8)
// =====================================================================
__global__ __launch_bounds__(256) void gemm_qkv(
        const ushort* __restrict__ xb, const ushort* __restrict__ Wb,
        const float* __restrict__ bq, const float* __restrict__ bk,
        const float* __restrict__ bv,
        ushort* __restrict__ qb, ushort* __restrict__ kb,
        ushort* __restrict__ vT) {
    __shared__ ushort As[2][LDSZ];
    __shared__ ushort Bs[2][LDSZ];
    const int m0   = blockIdx.x * 128;
    const int nt   = blockIdx.y;           // 0..23
    const int wsel = nt >> 3;
    const int n0   = (nt & 7) * 128;
    const ushort* W    = Wb + ((size_t)wsel << 20);
    const float* bias  = (wsel == 0) ? bq : (wsel == 1) ? bk : bv;

    const int t = threadIdx.x, lane = t & 63, wave = t >> 6;
    const int ln = lane & 15, quad = lane >> 4;
    const int wm = wave & 1, wn = wave >> 1;

    const int e0 = wave * 128 + lane;
    const int e1 = e0 + 64;
    const ushort* gA0 = xb + (size_t)(m0 + (e0 >> 2)) * 1024 + (e0 & 3) * 8;
    const ushort* gA1 = xb + (size_t)(m0 + (e1 >> 2)) * 1024 + (e1 & 3) * 8;
    const ushort* gB0 = W  + (size_t)(n0 + (e0 >> 2)) * 1024 + (e0 & 3) * 8;
    const ushort* gB1 = W  + (size_t)(n0 + (e1 >> 2)) * 1024 + (e1 & 3) * 8;
    ushort* lA0a = &As[0][wave * 1024]; ushort* lA0b = lA0a + 512;
    ushort* lA1a = &As[1][wave * 1024]; ushort* lA1b = lA1a + 512;
    ushort* lB0a = &Bs[0][wave * 1024]; ushort* lB0b = lB0a + 512;
    ushort* lB1a = &Bs[1][wave * 1024]; ushort* lB1b = lB1a + 512;

    f32x4 acc[4][4];
#pragma unroll
    for (int i = 0; i < 4; i++)
#pragma unroll
        for (int j = 0; j < 4; j++) acc[i][j] = (f32x4){0.f, 0.f, 0.f, 0.f};

    for (int k0 = 0; k0 < 1024; k0 += 64) {
        __syncthreads();
        gload16(gA0 + k0,      lA0a); gload16(gA1 + k0,      lA0b);
        gload16(gB0 + k0,      lB0a); gload16(gB1 + k0,      lB0b);
        gload16(gA0 + k0 + 32, lA1a); gload16(gA1 + k0 + 32, lA1b);
        gload16(gB0 + k0 + 32, lB1a); gload16(gB1 + k0 + 32, lB1b);
        __syncthreads();
#pragma unroll
        for (int kk2 = 0; kk2 < 2; kk2++) {
            bf16x8 af[4], bfr[4];
#pragma unroll
            for (int i = 0; i < 4; i++)
                af[i]  = *(bf16x8*)&As[kk2][(wm * 64 + i * 16 + ln) * 32 + quad * 8];
#pragma unroll
            for (int j = 0; j < 4; j++)
                bfr[j] = *(bf16x8*)&Bs[kk2][(wn * 64 + j * 16 + ln) * 32 + quad * 8];
#pragma unroll
            for (int i = 0; i < 4; i++)
#pragma unroll
                for (int j = 0; j < 4; j++)
                    acc[i][j] = __builtin_amdgcn_mfma_f32_16x16x32_bf16(
                                    af[i], bfr[j], acc[i][j], 0, 0, 0);
        }
    }

    if (wsel < 2) {
        ushort* dst = (wsel == 0) ? qb : kb;
        const float scale = (wsel == 0) ? 0.125f : 1.0f;   // q pre-scaled
#pragma unroll
        for (int j = 0; j < 4; j++) {
            const int o  = n0 + wn * 64 + j * 16 + ln;
            const float bval = bias[o];
            const int h = o >> 6, d = o & 63;
#pragma unroll
            for (int i = 0; i < 4; i++) {
                const int mg = m0 + wm * 64 + i * 16 + quad * 4;
#pragma unroll
                for (int r = 0; r < 4; r++) {
                    const int m  = mg + r;
                    const int b  = m >> 11;
                    const int ns = m & 2047;
                    dst[(size_t)(b * NH + h) * BHSTRIDE + (size_t)ns * HD + d] =
                        f2b((acc[i][j][r] + bval) * scale);
                }
            }
        }
    } else {
        // V transposed: vT[(b*NH+h)*BHSTRIDE + d*SEQN + n]
#pragma unroll
        for (int j = 0; j < 4; j++) {
            const int o  = n0 + wn * 64 + j * 16 + ln;
            const float bval = bias[o];
            const int h = o >> 6, d = o & 63;
#pragma unroll
            for (int i = 0; i < 4; i++) {
                const int mg = m0 + wm * 64 + i * 16 + quad * 4;
                const int b  = mg >> 11;
                const int ns = mg & 2047;
                ushort pk[4];
#pragma unroll
                for (int r = 0; r < 4; r++) pk[r] = f2b(acc[i][j][r] + bval);
                *(uint2*)&vT[(size_t)(b * NH + h) * BHSTRIDE +
                             (size_t)d * SEQN + ns] = *(uint2*)&pk[0];
            }
        }
    }
}

// =====================================================================
// Kernel 2: distance-biased attention — round-5 CODE with NATURAL block
// mapping (round-11 A/B: the untested cell of the {mapping x L-pipeline}
// matrix).  Natural mapping gives per-XCD L-slice locality (blocks
// sharing a q-tile sit at wid stride 16 -> same XCD under %8; 2 MB
// L-footprint fits L2) and measured 199 MB FETCH (R6) vs the remap's
// 283 MB.  dbuf K/V, 1 barrier/kt, hoisted L loads, setprio.  Deeper
// L-pipelining regresses via scratch spill (R6/R7); do not re-add.
// grid = (16,16,4); 4 waves; LDS 36 KB.
// =====================================================================
__global__ __launch_bounds__(256, 4) void attn(
        ushort* q,                     // aliased in/out (no restrict)
        const ushort* __restrict__ k,
        const ushort* __restrict__ vT,
        const float* __restrict__ Lp) {
    __shared__ short Ks[2][64 * 72];   // [buf][kv][d]
    __shared__ short Vs[2][64 * 72];   // [buf][d][kv]
    const int t = threadIdx.x, lane = t & 63, wave = t >> 6;
    const int lo = lane & 31, hi = lane >> 5;
    // ---- natural mapping (XCD remap removed this round) ----
    const int h = blockIdx.y, b = blockIdx.z;
    const int bh = b * NH + h;
    const int qw0 = blockIdx.x * 128 + wave * 32;   // this wave's 32 q-rows

    ushort* qp = q + (size_t)bh * BHSTRIDE;
    const ushort* kp = k  + (size_t)bh * BHSTRIDE;
    const ushort* vp = vT + (size_t)bh * BHSTRIDE;
    // permuted L: lane's base covers (qt = qw0>>5, lo); step = kv4*32 float4s
    const float4* Lp4 = (const float4*)Lp + ((size_t)(qw0 >> 5) * 512) * 32 + lo;

    // staging coords: thread t covers row sr, 16-short chunk sc
    const int sr = t >> 2;           // 0..63
    const int sc = (t & 3) * 16;     // 0,16,32,48

    // Q B-fragments: B[j=q=lo][k=d: kk*16 + hi*8 + c]
    bf16x8 qf[4];
#pragma unroll
    for (int kk = 0; kk < 4; kk++)
        qf[kk] = *(const bf16x8*)(qp + (size_t)(qw0 + lo) * HD + kk * 16 + hi * 8);

    f32x16 O[2];                     // O^T accum: rows d, col q=lo
#pragma unroll
    for (int dt = 0; dt < 2; dt++)
#pragma unroll
        for (int i = 0; i < 16; i++) O[dt][i] = 0.f;
    float lsum = 0.f;

    // ---- prologue: tile 0 -> buf0, tile 1 -> regs ----
    uint4 krg0 = *(const uint4*)(kp + (size_t)sr * HD + sc);
    uint4 krg1 = *(const uint4*)(kp + (size_t)sr * HD + sc + 8);
    uint4 vrg0 = *(const uint4*)(vp + (size_t)sr * SEQN + sc);
    uint4 vrg1 = *(const uint4*)(vp + (size_t)sr * SEQN + sc + 8);
    *(uint4*)&Ks[0][sr * 72 + sc]     = krg0;
    *(uint4*)&Ks[0][sr * 72 + sc + 8] = krg1;
    *(uint4*)&Vs[0][sr * 72 + sc]     = vrg0;
    *(uint4*)&Vs[0][sr * 72 + sc + 8] = vrg1;
    krg0 = *(const uint4*)(kp + (size_t)(64 + sr) * HD + sc);
    krg1 = *(const uint4*)(kp + (size_t)(64 + sr) * HD + sc + 8);
    vrg0 = *(const uint4*)(vp + (size_t)sr * SEQN + 64 + sc);
    vrg1 = *(const uint4*)(vp + (size_t)sr * SEQN + 64 + sc + 8);

    for (int kt = 0; kt < 32; kt++) {
        const int kv0 = kt * 64;
        const int cb = kt & 1;       // compute buffer
        __syncthreads();             // buf[cb] visible; readers of buf[cb^1] done
        // ---- write tile kt+1 into alt buffer (overlaps others' compute) ----
        *(uint4*)&Ks[cb ^ 1][sr * 72 + sc]     = krg0;
        *(uint4*)&Ks[cb ^ 1][sr * 72 + sc + 8] = krg1;
        *(uint4*)&Vs[cb ^ 1][sr * 72 + sc]     = vrg0;
        *(uint4*)&Vs[cb ^ 1][sr * 72 + sc + 8] = vrg1;
        // ---- issue global loads for tile kt+2 (wrap: harmless) ----
        const int kvn = (kv0 + 128) & 2047;
        krg0 = *(const uint4*)(kp + (size_t)(kvn + sr) * HD + sc);
        krg1 = *(const uint4*)(kp + (size_t)(kvn + sr) * HD + sc + 8);
        vrg0 = *(const uint4*)(vp + (size_t)sr * SEQN + kvn + sc);
        vrg1 = *(const uint4*)(vp + (size_t)sr * SEQN + kvn + sc + 8);
        // ---- hoisted L loads for THIS tile (cover: ds_reads + QK^T) ----
        float4 lv2[2][4];
#pragma unroll
        for (int s = 0; s < 2; s++)
#pragma unroll
            for (int n = 0; n < 4; n++)
                lv2[s][n] = Lp4[((kv0 >> 2) + s * 8 + hi + 2 * n) * 32];

#pragma unroll
        for (int s = 0; s < 2; s++) {
            // ---- S^T = K Q^T for kv-subtile s (32 rows) ----
            f32x16 z;
#pragma unroll
            for (int i = 0; i < 16; i++) z[i] = 0.f;
            __builtin_amdgcn_s_setprio(1);
#pragma unroll
            for (int kk = 0; kk < 4; kk++) {
                bf16x8 kf = *(bf16x8*)&Ks[cb][(s * 32 + lo) * 72 + kk * 16 + hi * 8];
                z = __builtin_amdgcn_mfma_f32_32x32x16_bf16(kf, qf[kk], z, 0, 0, 0);
            }
            __builtin_amdgcn_s_setprio(0);
            // ---- p = exp2(s*log2e + L); lane-local row sum ----
            // z[n*4+m] <-> kv = kv0 + s*32 + 4*hi + 8*n + m
            float p[16];
#pragma unroll
            for (int n = 0; n < 4; n++) {
#pragma unroll
                for (int m = 0; m < 4; m++) {
                    float pv = EXP2(fmaf(z[n * 4 + m], 1.44269504f,
                                         ((const float*)&lv2[s][n])[m]));
                    lsum += pv;
                    p[n * 4 + m] = pv;
                }
            }
            // ---- pack to PV B-fragments in-register + PV MFMA ----
#pragma unroll
            for (int kl = 0; kl < 2; kl++) {
                unsigned a0 = cvtpk(p[kl * 8 + 0], p[kl * 8 + 1]);
                unsigned b0 = cvtpk(p[kl * 8 + 4], p[kl * 8 + 5]);
                plswap(a0, b0);          // a0 -> word0, b0 -> word2
                unsigned a1 = cvtpk(p[kl * 8 + 2], p[kl * 8 + 3]);
                unsigned b1 = cvtpk(p[kl * 8 + 6], p[kl * 8 + 7]);
                plswap(a1, b1);          // a1 -> word1, b1 -> word3
                union { bf16x8 v; unsigned u[4]; } pf;
                pf.u[0] = a0; pf.u[1] = a1; pf.u[2] = b0; pf.u[3] = b1;
                const int kvk = s * 2 + kl;      // 16-kv block within tile
                __builtin_amdgcn_s_setprio(1);
#pragma unroll
                for (int dt = 0; dt < 2; dt++) {
                    bf16x8 vf = *(bf16x8*)&Vs[cb][(dt * 32 + lo) * 72 +
                                                  kvk * 16 + hi * 8];
                    O[dt] = __builtin_amdgcn_mfma_f32_32x32x16_bf16(
                                vf, pf.v, O[dt], 0, 0, 0);
                }
                __builtin_amdgcn_s_setprio(0);
            }
        }
    }

    // denominator: hi halves hold kv-disjoint partial sums for q=lo
    float tot = lsum + __shfl_xor(lsum, 32);
    const float inv = 1.0f / tot;
    // store O^T: d = dt*32 + 4*hi + 8*n + m, q = qw0+lo; pack 4 -> uint2
#pragma unroll
    for (int dt = 0; dt < 2; dt++)
#pragma unroll
        for (int n = 0; n < 4; n++) {
            uint2 pk2;
            pk2.x = cvtpk(O[dt][n * 4 + 0] * inv, O[dt][n * 4 + 1] * inv);
            pk2.y = cvtpk(O[dt][n * 4 + 2] * inv, O[dt][n * 4 + 3] * inv);
            *(uint2*)(qp + (size_t)(qw0 + lo) * HD + dt * 32 + hi * 4 + n * 8)
                = pk2;
        }
}

// =====================================================================
// Kernel 3: output projection -> d_out.  grid = (M/128, 8), BK=64
// (round-5 structure verbatim).  NOTE: natural block order already has
// A-tile XCD locality here (blocks sharing m0 sit at wid stride 64 ->
// same XCD under %8) — analyzed, do not remap.
// =====================================================================
__global__ __launch_bounds__(256) void gemm_out(
        const ushort* __restrict__ ao, const ushort* __restrict__ Wob,
        const float* __restrict__ bias, float* __restrict__ out) {
    __shared__ ushort As[2][LDSZ];
    __shared__ ushort Bs[2][LDSZ];
    const int m0 = blockIdx.x * 128;
    const int n0 = blockIdx.y * 128;
    const int t = threadIdx.x, lane = t & 63, wave = t >> 6;
    const int ln = lane & 15, quad = lane >> 4;
    const int wm = wave & 1, wn = wave >> 1;

    const int e0 = wave * 128 + lane;
    const int e1 = e0 + 64;
    const int bb = m0 >> 11;
    const int nbase = m0 & 2047;
    const ushort* gA0 = ao + ((size_t)bb << 21) +
                        (size_t)(nbase + (e0 >> 2)) * 64 + (e0 & 3) * 8;
    const ushort* gA1 = ao + ((size_t)bb << 21) +
                        (size_t)(nbase + (e1 >> 2)) * 64 + (e1 & 3) * 8;
    const ushort* gB0 = Wob + (size_t)(n0 + (e0 >> 2)) * 1024 + (e0 & 3) * 8;
    const ushort* gB1 = Wob + (size_t)(n0 + (e1 >> 2)) * 1024 + (e1 & 3) * 8;
    ushort* lA0a = &As[0][wave * 1024]; ushort* lA0b = lA0a + 512;
    ushort* lA1a = &As[1][wave * 1024]; ushort* lA1b = lA1a + 512;
    ushort* lB0a = &Bs[0][wave * 1024]; ushort* lB0b = lB0a + 512;
    ushort* lB1a = &Bs[1][wave * 1024]; ushort* lB1b = lB1a + 512;

    f32x4 acc[4][4];
#pragma unroll
    for (int i = 0; i < 4; i++)
#pragma unroll
        for (int j = 0; j < 4; j++) acc[i][j] = (f32x4){0.f, 0.f, 0.f, 0.f};

    for (int k0 = 0; k0 < 1024; k0 += 64) {
        // A layout [B,H,N,D]: k0 multiple of 64 -> head h = k0>>6, d0 = 0/32
        const size_t aoff = ((size_t)(k0 >> 6) << 17);
        __syncthreads();
        gload16(gA0 + aoff,      lA0a); gload16(gA1 + aoff,      lA0b);
        gload16(gB0 + k0,        lB0a); gload16(gB1 + k0,        lB0b);
        gload16(gA0 + aoff + 32, lA1a); gload16(gA1 + aoff + 32, lA1b);
        gload16(gB0 + k0 + 32,   lB1a); gload16(gB1 + k0 + 32,   lB1b);
        __syncthreads();
#pragma unroll
        for (int kk2 = 0; kk2 < 2; kk2++) {
            bf16x8 af[4], bfr[4];
#pragma unroll
            for (int i = 0; i < 4; i++)
                af[i]  = *(bf16x8*)&As[kk2][(wm * 64 + i * 16 + ln) * 32 + quad * 8];
#pragma unroll
            for (int j = 0; j < 4; j++)
                bfr[j] = *(bf16x8*)&Bs[kk2][(wn * 64 + j * 16 + ln) * 32 + quad * 8];
#pragma unroll
            for (int i = 0; i < 4; i++)
#pragma unroll
                for (int j = 0; j < 4; j++)
                    acc[i][j] = __builtin_amdgcn_mfma_f32_16x16x32_bf16(
                                    af[i], bfr[j], acc[i][j], 0, 0, 0);
        }
    }

#pragma unroll
    for (int j = 0; j < 4; j++) {
        const int o = n0 + wn * 64 + j * 16 + ln;
        const float bval = bias[o];
#pragma unroll
        for (int i = 0; i < 4; i++) {
            const int mg = m0 + wm * 64 + i * 16 + quad * 4;
#pragma unroll
            for (int r = 0; r < 4; r++)
                out[(size_t)(mg + r) * EMB + o] = acc[i][j][r] + bval;
        }
    }
}

// =====================================================================
extern "C" void kernel_launch(void* const* d_in, const int* in_sizes, int n_in,
                              void* d_out, int out_size, void* d_ws, size_t ws_size,
                              hipStream_t stream) {
    const float* x    = (const float*)d_in[0];
    const float* dist = (const float*)d_in[1];
    const float* Wq   = (const float*)d_in[2];
    const float* bq   = (const float*)d_in[3];
    const float* Wk   = (const float*)d_in[4];
    const float* bk   = (const float*)d_in[5];
    const float* Wv   = (const float*)d_in[6];
    const float* bv   = (const float*)d_in[7];
    const float* Wo   = (const float*)d_in[8];
    const float* bo   = (const float*)d_in[9];
    const float* dw   = (const float*)d_in[10];
    const float* db   = (const float*)d_in[11];

    const size_t PLANE = (size_t)8192 * 1024;   // elems per [M,C] bf16 buffer
    ushort* qb = (ushort*)d_ws;                 // [B,H,N,D] bf16, later attn out
    ushort* kb = qb + PLANE;                    // [B,H,N,D] bf16
    ushort* xb = kb + PLANE;                    // x as bf16 [8192][1024]
    ushort* Wb = xb + PLANE;                    // [Wq;Wk;Wv;Wo] bf16
    // d_out (33.55 MB fp32) as scratch before gemm_out:
    ushort* vT = (ushort*)d_out;                // [B,H,D,N] bf16 (16.78 MB)
    float*  Lf = (float*)(vT + PLANE);          // permuted f32 L table (16.78 MB)

    dim3 blk(256);
    conv_all     <<<dim3(10240),     blk, 0, stream>>>(x, Wq, Wk, Wv, Wo,
                                                       dist, dw, db,
                                                       xb, Wb, Lf);
    gemm_qkv     <<<dim3(64, 24),    blk, 0, stream>>>(xb, Wb, bq, bk, bv,
                                                       qb, kb, vT);
    attn         <<<dim3(16, 16, 4), blk, 0, stream>>>(qb, kb, vT, Lf);
    gemm_out     <<<dim3(64, 8),     blk, 0, stream>>>(qb, Wb + 3 * (size_t)(1 << 20),
                                                       bo, (float*)d_out);
}